// Round 1
// baseline (377.566 us; speedup 1.0000x reference)
//
#include <hip/hip_runtime.h>
#include <stdint.h>

#define N_EMBD 1024
#define NHEAD  16
#define HDIM   64
#define BATCH  8
#define SEQ    1024
#define MROWS  (BATCH*SEQ)   // 8192

typedef __bf16 bf16x8 __attribute__((ext_vector_type(8)));
typedef float  f32x4  __attribute__((ext_vector_type(4)));

__device__ inline unsigned short f2bf(float f) {
  uint32_t u = __float_as_uint(f);
  u += 0x7FFFu + ((u >> 16) & 1u);   // RNE; inputs are finite
  return (unsigned short)(u >> 16);
}

__device__ inline f32x4 mfma_bf16(bf16x8 a, bf16x8 b, f32x4 c) {
  return __builtin_amdgcn_mfma_f32_16x16x32_bf16(a, b, c, 0, 0, 0);
}

__device__ inline void gload_lds16(const unsigned short* g, unsigned short* l) {
  __builtin_amdgcn_global_load_lds(
      (const __attribute__((address_space(1))) void*)g,
      (__attribute__((address_space(3))) void*)l,
      16, 0, 0);
}

// ---------------- cast f32 -> bf16 (vectorized) ----------------
__global__ __launch_bounds__(256) void cast_f32_bf16(
    const float* __restrict__ in, unsigned short* __restrict__ out, int n) {
  int i = (blockIdx.x * 256 + threadIdx.x) * 4;
  if (i >= n) return;
  float4 v = *(const float4*)(in + i);
  ushort4 o;
  o.x = f2bf(v.x); o.y = f2bf(v.y); o.z = f2bf(v.z); o.w = f2bf(v.w);
  *(ushort4*)(out + i) = o;
}

// ---------------- transpose + cast: in [K][N] f32 -> out [N][K] bf16 ----------------
__global__ __launch_bounds__(256) void transpose_cast(
    const float* __restrict__ in, unsigned short* __restrict__ out, int K, int N) {
  __shared__ unsigned short tile[64 * 72];
  int k0 = blockIdx.y * 64, n0 = blockIdx.x * 64;
  int t = threadIdx.x;
  {
    int col = (t & 15) * 4;
#pragma unroll
    for (int it = 0; it < 4; ++it) {
      int row = (t >> 4) + it * 16;
      float4 v = *(const float4*)(in + (size_t)(k0 + row) * N + n0 + col);
      ushort4 o;
      o.x = f2bf(v.x); o.y = f2bf(v.y); o.z = f2bf(v.z); o.w = f2bf(v.w);
      *(ushort4*)&tile[row * 72 + col] = o;
    }
  }
  __syncthreads();
  {
    int kcol = (t & 7) * 8;
#pragma unroll
    for (int it = 0; it < 2; ++it) {
      int nrow = (t >> 3) + it * 32;
      alignas(16) unsigned short tmp[8];
#pragma unroll
      for (int j = 0; j < 8; ++j) tmp[j] = tile[(kcol + j) * 72 + nrow];
      *(uint4*)(out + (size_t)(n0 + nrow) * K + k0 + kcol) = *(const uint4*)tmp;
    }
  }
}

// ---------------- GEMM core (m97 structure): A[M][1024] bf16 row-major, Bt[N][1024] bf16 ----------------
// 128x128 tile, BK=32, 4 waves (2x2), 4x4 16x16x32 MFMA per wave, global_load_lds width 16.
#define GEMM_CORE(A_, Bt_)                                                        \
  __shared__ unsigned short Al[128 * 32];                                         \
  __shared__ unsigned short Bl[128 * 32];                                         \
  const int K = 1024;                                                             \
  int tid = threadIdx.x;                                                          \
  int l = tid & 63;                                                               \
  int w = tid >> 6;                                                               \
  int wr = w >> 1, wc = w & 1;                                                    \
  int m0 = blockIdx.y * 128;                                                      \
  int n0 = blockIdx.x * 128;                                                      \
  f32x4 acc[4][4];                                                                \
  _Pragma("unroll") for (int i = 0; i < 4; ++i)                                   \
      _Pragma("unroll") for (int j = 0; j < 4; ++j)                               \
          _Pragma("unroll") for (int r = 0; r < 4; ++r) acc[i][j][r] = 0.0f;      \
  const unsigned short* ga0 = A_ + (size_t)(m0 + (tid >> 2)) * K + (tid & 3) * 8; \
  const unsigned short* ga1 = ga0 + (size_t)64 * K;                               \
  const unsigned short* gb0 = Bt_ + (size_t)(n0 + (tid >> 2)) * K + (tid & 3) * 8;\
  const unsigned short* gb1 = gb0 + (size_t)64 * K;                               \
  unsigned short* la0 = &Al[tid * 8];                                             \
  unsigned short* la1 = &Al[tid * 8 + 2048];                                      \
  unsigned short* lb0 = &Bl[tid * 8];                                             \
  unsigned short* lb1 = &Bl[tid * 8 + 2048];                                      \
  const unsigned short* pa = &Al[(wr * 64 + (l & 15)) * 32 + 8 * (l >> 4)];       \
  const unsigned short* pb = &Bl[(wc * 64 + (l & 15)) * 32 + 8 * (l >> 4)];       \
  for (int k0 = 0; k0 < K; k0 += 32) {                                            \
    __syncthreads();                                                              \
    gload_lds16(ga0 + k0, la0);                                                   \
    gload_lds16(ga1 + k0, la1);                                                   \
    gload_lds16(gb0 + k0, lb0);                                                   \
    gload_lds16(gb1 + k0, lb1);                                                   \
    __syncthreads();                                                              \
    bf16x8 af[4], bfv[4];                                                         \
    _Pragma("unroll") for (int i = 0; i < 4; ++i)                                 \
        af[i] = *(const bf16x8*)(pa + i * 16 * 32);                               \
    _Pragma("unroll") for (int j = 0; j < 4; ++j)                                 \
        bfv[j] = *(const bf16x8*)(pb + j * 16 * 32);                              \
    _Pragma("unroll") for (int i = 0; i < 4; ++i)                                 \
        _Pragma("unroll") for (int j = 0; j < 4; ++j)                             \
            acc[i][j] = mfma_bf16(af[i], bfv[j], acc[i][j]);                      \
  }

// QKV GEMM: N=3072. Epilogue scatters to Q [BH][T][64], K [BH][T][64], VT [BH][64][T], all bf16.
__global__ __launch_bounds__(256) void gemm_qkv(
    const unsigned short* __restrict__ A, const unsigned short* __restrict__ Bt,
    const float* __restrict__ bias,
    unsigned short* __restrict__ Qo, unsigned short* __restrict__ Ko,
    unsigned short* __restrict__ VTo) {
  GEMM_CORE(A, Bt)
#pragma unroll
  for (int i = 0; i < 4; ++i) {
    int mb = m0 + wr * 64 + i * 16 + 4 * (l >> 4);
    int bidx = mb >> 10;
    int t = mb & 1023;
#pragma unroll
    for (int j = 0; j < 4; ++j) {
      int n = n0 + wc * 64 + j * 16 + (l & 15);
      float bv = bias[n];
      int part = n >> 10;
      int nn = n & 1023;
      int h = nn >> 6, d = nn & 63;
      if (part == 2) {
        alignas(8) unsigned short pk[4];
#pragma unroll
        for (int r = 0; r < 4; ++r) pk[r] = f2bf(acc[i][j][r] + bv);
        *(ushort4*)&VTo[((size_t)(bidx * NHEAD + h) * HDIM + d) * SEQ + t] =
            *(const ushort4*)pk;
      } else {
        unsigned short* dst = (part == 0) ? Qo : Ko;
        size_t base = ((size_t)(bidx * NHEAD + h) * SEQ + t) * HDIM + d;
#pragma unroll
        for (int r = 0; r < 4; ++r) dst[base + (size_t)r * HDIM] = f2bf(acc[i][j][r] + bv);
      }
    }
  }
}

// Proj GEMM: N=1024, f32 output + bias.
__global__ __launch_bounds__(256) void gemm_proj(
    const unsigned short* __restrict__ A, const unsigned short* __restrict__ Bt,
    const float* __restrict__ bias, float* __restrict__ Out) {
  GEMM_CORE(A, Bt)
#pragma unroll
  for (int i = 0; i < 4; ++i) {
    int mb = m0 + wr * 64 + i * 16 + 4 * (l >> 4);
#pragma unroll
    for (int j = 0; j < 4; ++j) {
      int n = n0 + wc * 64 + j * 16 + (l & 15);
      float bv = bias[n];
#pragma unroll
      for (int r = 0; r < 4; ++r)
        Out[(size_t)(mb + r) * N_EMBD + n] = acc[i][j][r] + bv;
    }
  }
}

// ---------------- flash-style causal attention ----------------
// grid = B*H*(T/128); 4 waves, each owns 32 q-rows; KVBLK=64; K/V frags read from global (L2-resident).
__global__ __launch_bounds__(256) void attn_kernel(
    const unsigned short* __restrict__ Q, const unsigned short* __restrict__ Kv,
    const unsigned short* __restrict__ VT, unsigned short* __restrict__ Y) {
  __shared__ unsigned short p_lds[4 * 32 * 72];
  int tid = threadIdx.x, l = tid & 63, w = tid >> 6;
  int bid = blockIdx.x;
  int qi = bid & 7, bh = bid >> 3;
  int b = bh >> 4, h = bh & 15;
  int q0 = qi * 128;
  int wq = q0 + w * 32;
  const unsigned short* Qb = Q + (size_t)bh * SEQ * HDIM;
  const unsigned short* Kb = Kv + (size_t)bh * SEQ * HDIM;
  const unsigned short* Vb = VT + (size_t)bh * HDIM * SEQ;
  unsigned short* pw = &p_lds[w * 32 * 72];

  bf16x8 aq[2][2];
#pragma unroll
  for (int i = 0; i < 2; ++i)
#pragma unroll
    for (int ik = 0; ik < 2; ++ik)
      aq[i][ik] = *(const bf16x8*)&Qb[(size_t)(wq + i * 16 + (l & 15)) * HDIM + ik * 32 + 8 * (l >> 4)];

  float mrun[2][4], lsum[2][4];
  f32x4 acc_o[2][4];
#pragma unroll
  for (int i = 0; i < 2; ++i)
#pragma unroll
    for (int r = 0; r < 4; ++r) { mrun[i][r] = -3.0e38f; lsum[i][r] = 0.0f; }
#pragma unroll
  for (int i = 0; i < 2; ++i)
#pragma unroll
    for (int jd = 0; jd < 4; ++jd)
#pragma unroll
      for (int r = 0; r < 4; ++r) acc_o[i][jd][r] = 0.0f;

  int kv_end = q0 + 128;
  for (int kv0 = 0; kv0 < kv_end; kv0 += 64) {
    f32x4 s[2][4];
#pragma unroll
    for (int i = 0; i < 2; ++i)
#pragma unroll
      for (int j = 0; j < 4; ++j)
#pragma unroll
        for (int r = 0; r < 4; ++r) s[i][j][r] = 0.0f;

#pragma unroll
    for (int ik = 0; ik < 2; ++ik) {
#pragma unroll
      for (int j = 0; j < 4; ++j) {
        bf16x8 bk = *(const bf16x8*)&Kb[(size_t)(kv0 + j * 16 + (l & 15)) * HDIM + ik * 32 + 8 * (l >> 4)];
#pragma unroll
        for (int i = 0; i < 2; ++i) s[i][j] = mfma_bf16(aq[i][ik], bk, s[i][j]);
      }
    }

    bool need_mask = (kv0 + 63) > wq;
#pragma unroll
    for (int i = 0; i < 2; ++i)
#pragma unroll
      for (int j = 0; j < 4; ++j)
#pragma unroll
        for (int r = 0; r < 4; ++r) {
          float v = s[i][j][r] * 0.125f;
          if (need_mask) {
            int q = wq + i * 16 + 4 * (l >> 4) + r;
            int kv = kv0 + j * 16 + (l & 15);
            if (kv > q) v = -3.0e38f;
          }
          s[i][j][r] = v;
        }

    float psc[2][4];
#pragma unroll
    for (int i = 0; i < 2; ++i)
#pragma unroll
      for (int r = 0; r < 4; ++r) {
        float mx = fmaxf(fmaxf(s[i][0][r], s[i][1][r]), fmaxf(s[i][2][r], s[i][3][r]));
#pragma unroll
        for (int dd = 1; dd < 16; dd <<= 1) mx = fmaxf(mx, __shfl_xor(mx, dd, 64));
        float mn = fmaxf(mrun[i][r], mx);
        float sc = __expf(mrun[i][r] - mn);
        mrun[i][r] = mn;
        float ps = 0.0f;
#pragma unroll
        for (int j = 0; j < 4; ++j) {
          float p = __expf(s[i][j][r] - mn);
          ps += p;
          pw[(i * 16 + 4 * (l >> 4) + r) * 72 + j * 16 + (l & 15)] = f2bf(p);
        }
#pragma unroll
        for (int dd = 1; dd < 16; dd <<= 1) ps += __shfl_xor(ps, dd, 64);
        lsum[i][r] = lsum[i][r] * sc + ps;
        psc[i][r] = sc;
      }

#pragma unroll
    for (int i = 0; i < 2; ++i)
#pragma unroll
      for (int jd = 0; jd < 4; ++jd)
#pragma unroll
        for (int r = 0; r < 4; ++r) acc_o[i][jd][r] *= psc[i][r];

    __syncthreads();  // P writes visible (block-uniform trip count)
#pragma unroll
    for (int ik2 = 0; ik2 < 2; ++ik2) {
      bf16x8 ap[2];
#pragma unroll
      for (int i = 0; i < 2; ++i)
        ap[i] = *(const bf16x8*)&pw[(i * 16 + (l & 15)) * 72 + ik2 * 32 + 8 * (l >> 4)];
#pragma unroll
      for (int jd = 0; jd < 4; ++jd) {
        bf16x8 bv = *(const bf16x8*)&Vb[(size_t)(jd * 16 + (l & 15)) * SEQ + kv0 + ik2 * 32 + 8 * (l >> 4)];
#pragma unroll
        for (int i = 0; i < 2; ++i) acc_o[i][jd] = mfma_bf16(ap[i], bv, acc_o[i][jd]);
      }
    }
    __syncthreads();  // done reading P before next iteration overwrites
  }

#pragma unroll
  for (int i = 0; i < 2; ++i)
#pragma unroll
    for (int jd = 0; jd < 4; ++jd)
#pragma unroll
      for (int r = 0; r < 4; ++r) {
        int q = wq + i * 16 + 4 * (l >> 4) + r;
        float v = acc_o[i][jd][r] / lsum[i][r];
        Y[((size_t)b * SEQ + q) * N_EMBD + h * HDIM + jd * 16 + (l & 15)] = f2bf(v);
      }
}

// ---------------- launcher ----------------
extern "C" void kernel_launch(void* const* d_in, const int* in_sizes, int n_in,
                              void* d_out, int out_size, void* d_ws, size_t ws_size,
                              hipStream_t stream) {
  (void)in_sizes; (void)n_in; (void)out_size; (void)ws_size;
  const float* x      = (const float*)d_in[0];
  const float* w_attn = (const float*)d_in[1];
  const float* b_attn = (const float*)d_in[2];
  const float* w_proj = (const float*)d_in[3];
  const float* b_proj = (const float*)d_in[4];
  float* out = (float*)d_out;

  char* ws = (char*)d_ws;
  size_t off = 0;
  auto carve = [&](size_t bytes) -> char* {
    char* p = ws + off;
    off += (bytes + 255) & ~(size_t)255;
    return p;
  };
  unsigned short* xb     = (unsigned short*)carve((size_t)MROWS * N_EMBD * 2);
  unsigned short* wTattn = (unsigned short*)carve((size_t)3 * N_EMBD * N_EMBD * 2);
  unsigned short* wTproj = (unsigned short*)carve((size_t)N_EMBD * N_EMBD * 2);
  unsigned short* Qb     = (unsigned short*)carve((size_t)MROWS * N_EMBD * 2);
  unsigned short* Kb     = (unsigned short*)carve((size_t)MROWS * N_EMBD * 2);
  unsigned short* VTb    = (unsigned short*)carve((size_t)MROWS * N_EMBD * 2);
  unsigned short* Yb     = (unsigned short*)carve((size_t)MROWS * N_EMBD * 2);

  cast_f32_bf16<<<dim3(MROWS * N_EMBD / 1024), 256, 0, stream>>>(x, xb, MROWS * N_EMBD);
  transpose_cast<<<dim3(3 * N_EMBD / 64, N_EMBD / 64), 256, 0, stream>>>(w_attn, wTattn, N_EMBD, 3 * N_EMBD);
  transpose_cast<<<dim3(N_EMBD / 64, N_EMBD / 64), 256, 0, stream>>>(w_proj, wTproj, N_EMBD, N_EMBD);
  gemm_qkv<<<dim3(3 * N_EMBD / 128, MROWS / 128), 256, 0, stream>>>(xb, wTattn, b_attn, Qb, Kb, VTb);
  attn_kernel<<<dim3(BATCH * NHEAD * (SEQ / 128)), 256, 0, stream>>>(Qb, Kb, VTb, Yb);
  gemm_proj<<<dim3(N_EMBD / 128, MROWS / 128), 256, 0, stream>>>(Yb, wTproj, b_proj, out);
}

// Round 2
// 242.910 us; speedup vs baseline: 1.5543x; 1.5543x over previous
//
#include <hip/hip_runtime.h>
#include <stdint.h>

#define N_EMBD 1024
#define NHEAD  16
#define HDIM   64
#define BATCH  8
#define SEQ    1024
#define MROWS  (BATCH*SEQ)   // 8192

typedef __bf16 bf16x8 __attribute__((ext_vector_type(8)));
typedef float  f32x4  __attribute__((ext_vector_type(4)));

__device__ inline unsigned short f2bf(float f) {
  uint32_t u = __float_as_uint(f);
  u += 0x7FFFu + ((u >> 16) & 1u);   // RNE; inputs are finite
  return (unsigned short)(u >> 16);
}

__device__ inline f32x4 mfma_bf16(bf16x8 a, bf16x8 b, f32x4 c) {
  return __builtin_amdgcn_mfma_f32_16x16x32_bf16(a, b, c, 0, 0, 0);
}

__device__ inline void gload_lds16(const unsigned short* g, unsigned short* l) {
  __builtin_amdgcn_global_load_lds(
      (const __attribute__((address_space(1))) void*)g,
      (__attribute__((address_space(3))) void*)l,
      16, 0, 0);
}

// ---------------- cast f32 -> bf16 (vectorized) ----------------
__global__ __launch_bounds__(256) void cast_f32_bf16(
    const float* __restrict__ in, unsigned short* __restrict__ out, int n) {
  int i = (blockIdx.x * 256 + threadIdx.x) * 4;
  if (i >= n) return;
  float4 v = *(const float4*)(in + i);
  ushort4 o;
  o.x = f2bf(v.x); o.y = f2bf(v.y); o.z = f2bf(v.z); o.w = f2bf(v.w);
  *(ushort4*)(out + i) = o;
}

// ---------------- transpose + cast: in [K][N] f32 -> out [N][K] bf16 ----------------
__global__ __launch_bounds__(256) void transpose_cast(
    const float* __restrict__ in, unsigned short* __restrict__ out, int K, int N) {
  __shared__ unsigned short tile[64 * 72];
  int k0 = blockIdx.y * 64, n0 = blockIdx.x * 64;
  int t = threadIdx.x;
  {
    int col = (t & 15) * 4;
#pragma unroll
    for (int it = 0; it < 4; ++it) {
      int row = (t >> 4) + it * 16;
      float4 v = *(const float4*)(in + (size_t)(k0 + row) * N + n0 + col);
      ushort4 o;
      o.x = f2bf(v.x); o.y = f2bf(v.y); o.z = f2bf(v.z); o.w = f2bf(v.w);
      *(ushort4*)&tile[row * 72 + col] = o;
    }
  }
  __syncthreads();
  {
    int kcol = (t & 7) * 8;
#pragma unroll
    for (int it = 0; it < 2; ++it) {
      int nrow = (t >> 3) + it * 32;
      alignas(16) unsigned short tmp[8];
#pragma unroll
      for (int j = 0; j < 8; ++j) tmp[j] = tile[(kcol + j) * 72 + nrow];
      *(uint4*)(out + (size_t)(n0 + nrow) * K + k0 + kcol) = *(const uint4*)tmp;
    }
  }
}

// ---------------- GEMM core (m97 structure): A[M][1024] bf16 row-major, Bt[N][1024] bf16 ----------------
#define GEMM_CORE(A_, Bt_)                                                        \
  __shared__ unsigned short Al[128 * 32];                                         \
  __shared__ unsigned short Bl[128 * 32];                                         \
  const int K = 1024;                                                             \
  int tid = threadIdx.x;                                                          \
  int l = tid & 63;                                                               \
  int w = tid >> 6;                                                               \
  int wr = w >> 1, wc = w & 1;                                                    \
  int m0 = blockIdx.y * 128;                                                      \
  int n0 = blockIdx.x * 128;                                                      \
  f32x4 acc[4][4];                                                                \
  _Pragma("unroll") for (int i = 0; i < 4; ++i)                                   \
      _Pragma("unroll") for (int j = 0; j < 4; ++j)                               \
          _Pragma("unroll") for (int r = 0; r < 4; ++r) acc[i][j][r] = 0.0f;      \
  const unsigned short* ga0 = A_ + (size_t)(m0 + (tid >> 2)) * K + (tid & 3) * 8; \
  const unsigned short* ga1 = ga0 + (size_t)64 * K;                               \
  const unsigned short* gb0 = Bt_ + (size_t)(n0 + (tid >> 2)) * K + (tid & 3) * 8;\
  const unsigned short* gb1 = gb0 + (size_t)64 * K;                               \
  unsigned short* la0 = &Al[tid * 8];                                             \
  unsigned short* la1 = &Al[tid * 8 + 2048];                                      \
  unsigned short* lb0 = &Bl[tid * 8];                                             \
  unsigned short* lb1 = &Bl[tid * 8 + 2048];                                      \
  const unsigned short* pa = &Al[(wr * 64 + (l & 15)) * 32 + 8 * (l >> 4)];       \
  const unsigned short* pb = &Bl[(wc * 64 + (l & 15)) * 32 + 8 * (l >> 4)];       \
  for (int k0 = 0; k0 < K; k0 += 32) {                                            \
    __syncthreads();                                                              \
    gload_lds16(ga0 + k0, la0);                                                   \
    gload_lds16(ga1 + k0, la1);                                                   \
    gload_lds16(gb0 + k0, lb0);                                                   \
    gload_lds16(gb1 + k0, lb1);                                                   \
    __syncthreads();                                                              \
    bf16x8 af[4], bfv[4];                                                         \
    _Pragma("unroll") for (int i = 0; i < 4; ++i)                                 \
        af[i] = *(const bf16x8*)(pa + i * 16 * 32);                               \
    _Pragma("unroll") for (int j = 0; j < 4; ++j)                                 \
        bfv[j] = *(const bf16x8*)(pb + j * 16 * 32);                              \
    _Pragma("unroll") for (int i = 0; i < 4; ++i)                                 \
        _Pragma("unroll") for (int j = 0; j < 4; ++j)                             \
            acc[i][j] = mfma_bf16(af[i], bfv[j], acc[i][j]);                      \
  }

// QKV GEMM: N=3072. Epilogue scatters to Q (scaled by 1/8) [BH][T][64], K [BH][T][64], VT [BH][64][T].
__global__ __launch_bounds__(256) void gemm_qkv(
    const unsigned short* __restrict__ A, const unsigned short* __restrict__ Bt,
    const float* __restrict__ bias,
    unsigned short* __restrict__ Qo, unsigned short* __restrict__ Ko,
    unsigned short* __restrict__ VTo) {
  GEMM_CORE(A, Bt)
#pragma unroll
  for (int i = 0; i < 4; ++i) {
    int mb = m0 + wr * 64 + i * 16 + 4 * (l >> 4);
    int bidx = mb >> 10;
    int t = mb & 1023;
#pragma unroll
    for (int j = 0; j < 4; ++j) {
      int n = n0 + wc * 64 + j * 16 + (l & 15);
      float bv = bias[n];
      int part = n >> 10;
      int nn = n & 1023;
      int h = nn >> 6, d = nn & 63;
      if (part == 2) {
        alignas(8) unsigned short pk[4];
#pragma unroll
        for (int r = 0; r < 4; ++r) pk[r] = f2bf(acc[i][j][r] + bv);
        *(ushort4*)&VTo[((size_t)(bidx * NHEAD + h) * HDIM + d) * SEQ + t] =
            *(const ushort4*)pk;
      } else {
        unsigned short* dst = (part == 0) ? Qo : Ko;
        float scl = (part == 0) ? 0.125f : 1.0f;   // fold 1/sqrt(hd) into Q
        size_t base = ((size_t)(bidx * NHEAD + h) * SEQ + t) * HDIM + d;
#pragma unroll
        for (int r = 0; r < 4; ++r) dst[base + (size_t)r * HDIM] = f2bf((acc[i][j][r] + bv) * scl);
      }
    }
  }
}

// Proj GEMM: N=1024, f32 output + bias.
__global__ __launch_bounds__(256) void gemm_proj(
    const unsigned short* __restrict__ A, const unsigned short* __restrict__ Bt,
    const float* __restrict__ bias, float* __restrict__ Out) {
  GEMM_CORE(A, Bt)
#pragma unroll
  for (int i = 0; i < 4; ++i) {
    int mb = m0 + wr * 64 + i * 16 + 4 * (l >> 4);
#pragma unroll
    for (int j = 0; j < 4; ++j) {
      int n = n0 + wc * 64 + j * 16 + (l & 15);
      float bv = bias[n];
#pragma unroll
      for (int r = 0; r < 4; ++r)
        Out[(size_t)(mb + r) * N_EMBD + n] = acc[i][j][r] + bv;
    }
  }
}

// ---------------- flash-style causal attention, LDS-staged K/V, double-buffered ----------------
// grid = B*H*(T/128); 4 waves x 32 q-rows. KVBLK=64. K tile [64][64] bf16 + V tile [64 d][64 kv],
// both XOR-swizzled (byte ^= (row&7)<<4) via pre-swizzled global source (gload_lds writes linearly).
__global__ __launch_bounds__(256) void attn_kernel(
    const unsigned short* __restrict__ Q, const unsigned short* __restrict__ Kv,
    const unsigned short* __restrict__ VT, unsigned short* __restrict__ Y) {
  __shared__ unsigned short Kt[2][4096];
  __shared__ unsigned short Vt[2][4096];
  __shared__ unsigned short p_lds[4 * 32 * 72];
  int tid = threadIdx.x, l = tid & 63, w = tid >> 6;
  int bid = blockIdx.x;
  int qi = bid & 7, bh = bid >> 3;
  int b = bh >> 4, h = bh & 15;
  int q0 = qi * 128;
  int wq = q0 + w * 32;
  const unsigned short* Qb = Q + (size_t)bh * SEQ * HDIM;
  const char* Kc = (const char*)(Kv + (size_t)bh * SEQ * HDIM);
  const char* Vc = (const char*)(VT + (size_t)bh * HDIM * SEQ);
  unsigned short* pw = &p_lds[w * 32 * 72];

  // staging geometry: thread owns 16B at linear tile byte offset P0 (call0) / P1 (call1).
  // LDS stays linear; global source is pre-swizzled so LDS[row*128 + (c ^ ((row&7)<<4))] = G[row][c].
  const int P0 = tid * 16, P1 = tid * 16 + 4096;
  const int r0 = P0 >> 7, r1 = P1 >> 7;
  const int s0 = (P0 & 127) ^ ((r0 & 7) << 4);
  const int s1 = (P1 & 127) ^ ((r1 & 7) << 4);
  const char* Kg0 = Kc + r0 * 128 + s0;   // K rows contiguous (tile is 8KB contiguous)
  const char* Kg1 = Kc + r1 * 128 + s1;
  const char* Vg0 = Vc + (size_t)r0 * 2048 + s0;  // VT row stride = SEQ*2 bytes
  const char* Vg1 = Vc + (size_t)r1 * 2048 + s1;

  // per-lane swizzled fragment-read geometry
  const int fr = l & 15;
  const int bc = (16 * (l >> 4)) ^ ((l & 7) << 4);  // swizzled col byte base; ^ (ik<<6) selects k-half

  bf16x8 aq[2][2];
#pragma unroll
  for (int i = 0; i < 2; ++i)
#pragma unroll
    for (int ik = 0; ik < 2; ++ik)
      aq[i][ik] = *(const bf16x8*)&Qb[(size_t)(wq + i * 16 + fr) * HDIM + ik * 32 + 8 * (l >> 4)];

  float mrun[2][4], lsum[2][4];
  f32x4 acc_o[2][4];
#pragma unroll
  for (int i = 0; i < 2; ++i)
#pragma unroll
    for (int r = 0; r < 4; ++r) { mrun[i][r] = -3.0e38f; lsum[i][r] = 0.0f; }
#pragma unroll
  for (int i = 0; i < 2; ++i)
#pragma unroll
    for (int jd = 0; jd < 4; ++jd)
#pragma unroll
      for (int r = 0; r < 4; ++r) acc_o[i][jd][r] = 0.0f;

  const int n_it = (q0 + 128) >> 6;  // >= 2, block-uniform

  stage_k0:;
  // prologue: stage tile 0
  gload_lds16((const unsigned short*)(Kg0), &Kt[0][P0 >> 1]);
  gload_lds16((const unsigned short*)(Kg1), &Kt[0][P1 >> 1]);
  gload_lds16((const unsigned short*)(Vg0), &Vt[0][P0 >> 1]);
  gload_lds16((const unsigned short*)(Vg1), &Vt[0][P1 >> 1]);

  for (int it = 0; it < n_it; ++it) {
    const int kv0 = it << 6;
    const int cur = it & 1;
    if (it + 1 < n_it) {
      const int nx = kv0 + 64;
      gload_lds16((const unsigned short*)(Kg0 + nx * 128), &Kt[cur ^ 1][P0 >> 1]);
      gload_lds16((const unsigned short*)(Kg1 + nx * 128), &Kt[cur ^ 1][P1 >> 1]);
      gload_lds16((const unsigned short*)(Vg0 + nx * 2),   &Vt[cur ^ 1][P0 >> 1]);
      gload_lds16((const unsigned short*)(Vg1 + nx * 2),   &Vt[cur ^ 1][P1 >> 1]);
      asm volatile("s_waitcnt vmcnt(4)" ::: "memory");  // current tile (older 4) done
    } else {
      asm volatile("s_waitcnt vmcnt(0)" ::: "memory");
    }
    __builtin_amdgcn_sched_barrier(0);
    __builtin_amdgcn_s_barrier();   // all waves' stages of tile `cur` visible
    __builtin_amdgcn_sched_barrier(0);

    const char* Kbuf = (const char*)Kt[cur];
    const char* Vbuf = (const char*)Vt[cur];

    f32x4 s[2][4];
#pragma unroll
    for (int i = 0; i < 2; ++i)
#pragma unroll
      for (int j = 0; j < 4; ++j)
#pragma unroll
        for (int r = 0; r < 4; ++r) s[i][j][r] = 0.0f;

    __builtin_amdgcn_s_setprio(1);
#pragma unroll
    for (int ik = 0; ik < 2; ++ik) {
#pragma unroll
      for (int j = 0; j < 4; ++j) {
        bf16x8 bk = *(const bf16x8*)(Kbuf + (j * 16 + fr) * 128 + (bc ^ (ik << 6)));
#pragma unroll
        for (int i = 0; i < 2; ++i) s[i][j] = mfma_bf16(aq[i][ik], bk, s[i][j]);
      }
    }
    __builtin_amdgcn_s_setprio(0);

    bool need_mask = (kv0 + 63) > wq;
#pragma unroll
    for (int i = 0; i < 2; ++i)
#pragma unroll
      for (int j = 0; j < 4; ++j)
#pragma unroll
        for (int r = 0; r < 4; ++r) {
          float v = s[i][j][r];   // Q pre-scaled by 1/8
          if (need_mask) {
            int q = wq + i * 16 + 4 * (l >> 4) + r;
            int kv = kv0 + j * 16 + fr;
            if (kv > q) v = -3.0e38f;
          }
          s[i][j][r] = v;
        }

    float psc[2][4];
#pragma unroll
    for (int i = 0; i < 2; ++i)
#pragma unroll
      for (int r = 0; r < 4; ++r) {
        float mx = fmaxf(fmaxf(s[i][0][r], s[i][1][r]), fmaxf(s[i][2][r], s[i][3][r]));
#pragma unroll
        for (int dd = 1; dd < 16; dd <<= 1) mx = fmaxf(mx, __shfl_xor(mx, dd, 64));
        float mn = fmaxf(mrun[i][r], mx);
        float sc = __expf(mrun[i][r] - mn);
        mrun[i][r] = mn;
        float ps = 0.0f;
#pragma unroll
        for (int j = 0; j < 4; ++j) {
          float p = __expf(s[i][j][r] - mn);
          ps += p;
          pw[(i * 16 + 4 * (l >> 4) + r) * 72 + j * 16 + fr] = f2bf(p);
        }
#pragma unroll
        for (int dd = 1; dd < 16; dd <<= 1) ps += __shfl_xor(ps, dd, 64);
        lsum[i][r] = lsum[i][r] * sc + ps;
        psc[i][r] = sc;
      }

#pragma unroll
    for (int i = 0; i < 2; ++i)
#pragma unroll
      for (int jd = 0; jd < 4; ++jd)
#pragma unroll
        for (int r = 0; r < 4; ++r) acc_o[i][jd][r] *= psc[i][r];

    // P is per-wave-private LDS: no cross-wave barrier needed; compiler orders ds_write->ds_read.
    __builtin_amdgcn_s_setprio(1);
#pragma unroll
    for (int ik2 = 0; ik2 < 2; ++ik2) {
      bf16x8 ap[2];
#pragma unroll
      for (int i = 0; i < 2; ++i)
        ap[i] = *(const bf16x8*)&pw[(i * 16 + fr) * 72 + ik2 * 32 + 8 * (l >> 4)];
#pragma unroll
      for (int jd = 0; jd < 4; ++jd) {
        bf16x8 bv = *(const bf16x8*)(Vbuf + (jd * 16 + fr) * 128 + (bc ^ (ik2 << 6)));
#pragma unroll
        for (int i = 0; i < 2; ++i) acc_o[i][jd] = mfma_bf16(ap[i], bv, acc_o[i][jd]);
      }
    }
    __builtin_amdgcn_s_setprio(0);

    // end-of-iteration barrier: all waves done READING buf `cur` before next iter overwrites it
    asm volatile("s_waitcnt lgkmcnt(0)" ::: "memory");
    __builtin_amdgcn_sched_barrier(0);
    __builtin_amdgcn_s_barrier();
    __builtin_amdgcn_sched_barrier(0);
  }

#pragma unroll
  for (int i = 0; i < 2; ++i)
#pragma unroll
    for (int jd = 0; jd < 4; ++jd)
#pragma unroll
      for (int r = 0; r < 4; ++r) {
        int q = wq + i * 16 + 4 * (l >> 4) + r;
        float v = acc_o[i][jd][r] / lsum[i][r];
        Y[((size_t)b * SEQ + q) * N_EMBD + h * HDIM + jd * 16 + fr] = f2bf(v);
      }
}

// ---------------- launcher ----------------
extern "C" void kernel_launch(void* const* d_in, const int* in_sizes, int n_in,
                              void* d_out, int out_size, void* d_ws, size_t ws_size,
                              hipStream_t stream) {
  (void)in_sizes; (void)n_in; (void)out_size; (void)ws_size;
  const float* x      = (const float*)d_in[0];
  const float* w_attn = (const float*)d_in[1];
  const float* b_attn = (const float*)d_in[2];
  const float* w_proj = (const float*)d_in[3];
  const float* b_proj = (const float*)d_in[4];
  float* out = (float*)d_out;

  char* ws = (char*)d_ws;
  size_t off = 0;
  auto carve = [&](size_t bytes) -> char* {
    char* p = ws + off;
    off += (bytes + 255) & ~(size_t)255;
    return p;
  };
  unsigned short* xb     = (unsigned short*)carve((size_t)MROWS * N_EMBD * 2);
  unsigned short* wTattn = (unsigned short*)carve((size_t)3 * N_EMBD * N_EMBD * 2);
  unsigned short* wTproj = (unsigned short*)carve((size_t)N_EMBD * N_EMBD * 2);
  unsigned short* Qb     = (unsigned short*)carve((size_t)MROWS * N_EMBD * 2);
  unsigned short* Kb     = (unsigned short*)carve((size_t)MROWS * N_EMBD * 2);
  unsigned short* VTb    = (unsigned short*)carve((size_t)MROWS * N_EMBD * 2);
  unsigned short* Yb     = (unsigned short*)carve((size_t)MROWS * N_EMBD * 2);

  cast_f32_bf16<<<dim3(MROWS * N_EMBD / 1024), 256, 0, stream>>>(x, xb, MROWS * N_EMBD);
  transpose_cast<<<dim3(3 * N_EMBD / 64, N_EMBD / 64), 256, 0, stream>>>(w_attn, wTattn, N_EMBD, 3 * N_EMBD);
  transpose_cast<<<dim3(N_EMBD / 64, N_EMBD / 64), 256, 0, stream>>>(w_proj, wTproj, N_EMBD, N_EMBD);
  gemm_qkv<<<dim3(3 * N_EMBD / 128, MROWS / 128), 256, 0, stream>>>(xb, wTattn, b_attn, Qb, Kb, VTb);
  attn_kernel<<<dim3(BATCH * NHEAD * (SEQ / 128)), 256, 0, stream>>>(Qb, Kb, VTb, Yb);
  gemm_proj<<<dim3(N_EMBD / 128, MROWS / 128), 256, 0, stream>>>(Yb, wTproj, b_proj, out);
}

// Round 3
// 197.784 us; speedup vs baseline: 1.9090x; 1.2282x over previous
//
#include <hip/hip_runtime.h>
#include <stdint.h>

#define N_EMBD 1024
#define NHEAD  16
#define HDIM   64
#define BATCH  8
#define SEQ    1024
#define MROWS  (BATCH*SEQ)   // 8192

typedef __bf16 bf16x8 __attribute__((ext_vector_type(8)));
typedef float  f32x4  __attribute__((ext_vector_type(4)));

__device__ inline unsigned short f2bf(float f) {
  uint32_t u = __float_as_uint(f);
  u += 0x7FFFu + ((u >> 16) & 1u);   // RNE; inputs are finite
  return (unsigned short)(u >> 16);
}

__device__ inline f32x4 mfma_bf16(bf16x8 a, bf16x8 b, f32x4 c) {
  return __builtin_amdgcn_mfma_f32_16x16x32_bf16(a, b, c, 0, 0, 0);
}

__device__ inline void gload_lds16(const unsigned short* g, unsigned short* l) {
  __builtin_amdgcn_global_load_lds(
      (const __attribute__((address_space(1))) void*)g,
      (__attribute__((address_space(3))) void*)l,
      16, 0, 0);
}

// ---------------- cast f32 -> bf16 (vectorized) ----------------
__global__ __launch_bounds__(256) void cast_f32_bf16(
    const float* __restrict__ in, unsigned short* __restrict__ out, int n) {
  int i = (blockIdx.x * 256 + threadIdx.x) * 4;
  if (i >= n) return;
  float4 v = *(const float4*)(in + i);
  ushort4 o;
  o.x = f2bf(v.x); o.y = f2bf(v.y); o.z = f2bf(v.z); o.w = f2bf(v.w);
  *(ushort4*)(out + i) = o;
}

// ---------------- transpose + cast: in [K][N] f32 -> out [N][K] bf16 ----------------
__global__ __launch_bounds__(256) void transpose_cast(
    const float* __restrict__ in, unsigned short* __restrict__ out, int K, int N) {
  __shared__ unsigned short tile[64 * 72];
  int k0 = blockIdx.y * 64, n0 = blockIdx.x * 64;
  int t = threadIdx.x;
  {
    int col = (t & 15) * 4;
#pragma unroll
    for (int it = 0; it < 4; ++it) {
      int row = (t >> 4) + it * 16;
      float4 v = *(const float4*)(in + (size_t)(k0 + row) * N + n0 + col);
      ushort4 o;
      o.x = f2bf(v.x); o.y = f2bf(v.y); o.z = f2bf(v.z); o.w = f2bf(v.w);
      *(ushort4*)&tile[row * 72 + col] = o;
    }
  }
  __syncthreads();
  {
    int kcol = (t & 7) * 8;
#pragma unroll
    for (int it = 0; it < 2; ++it) {
      int nrow = (t >> 3) + it * 32;
      alignas(16) unsigned short tmp[8];
#pragma unroll
      for (int j = 0; j < 8; ++j) tmp[j] = tile[(kcol + j) * 72 + nrow];
      *(uint4*)(out + (size_t)(n0 + nrow) * K + k0 + kcol) = *(const uint4*)tmp;
    }
  }
}

// ---------------- GEMM core (m97 structure): A[M][1024] bf16 row-major, Bt[N][1024] bf16 ----------------
#define GEMM_CORE(A_, Bt_)                                                        \
  __shared__ unsigned short Al[128 * 32];                                         \
  __shared__ unsigned short Bl[128 * 32];                                         \
  const int K = 1024;                                                             \
  int tid = threadIdx.x;                                                          \
  int l = tid & 63;                                                               \
  int w = tid >> 6;                                                               \
  int wr = w >> 1, wc = w & 1;                                                    \
  int m0 = blockIdx.y * 128;                                                      \
  int n0 = blockIdx.x * 128;                                                      \
  f32x4 acc[4][4];                                                                \
  _Pragma("unroll") for (int i = 0; i < 4; ++i)                                   \
      _Pragma("unroll") for (int j = 0; j < 4; ++j)                               \
          _Pragma("unroll") for (int r = 0; r < 4; ++r) acc[i][j][r] = 0.0f;      \
  const unsigned short* ga0 = A_ + (size_t)(m0 + (tid >> 2)) * K + (tid & 3) * 8; \
  const unsigned short* ga1 = ga0 + (size_t)64 * K;                               \
  const unsigned short* gb0 = Bt_ + (size_t)(n0 + (tid >> 2)) * K + (tid & 3) * 8;\
  const unsigned short* gb1 = gb0 + (size_t)64 * K;                               \
  unsigned short* la0 = &Al[tid * 8];                                             \
  unsigned short* la1 = &Al[tid * 8 + 2048];                                      \
  unsigned short* lb0 = &Bl[tid * 8];                                             \
  unsigned short* lb1 = &Bl[tid * 8 + 2048];                                      \
  const unsigned short* pa = &Al[(wr * 64 + (l & 15)) * 32 + 8 * (l >> 4)];       \
  const unsigned short* pb = &Bl[(wc * 64 + (l & 15)) * 32 + 8 * (l >> 4)];       \
  for (int k0 = 0; k0 < K; k0 += 32) {                                            \
    __syncthreads();                                                              \
    gload_lds16(ga0 + k0, la0);                                                   \
    gload_lds16(ga1 + k0, la1);                                                   \
    gload_lds16(gb0 + k0, lb0);                                                   \
    gload_lds16(gb1 + k0, lb1);                                                   \
    __syncthreads();                                                              \
    bf16x8 af[4], bfv[4];                                                         \
    _Pragma("unroll") for (int i = 0; i < 4; ++i)                                 \
        af[i] = *(const bf16x8*)(pa + i * 16 * 32);                               \
    _Pragma("unroll") for (int j = 0; j < 4; ++j)                                 \
        bfv[j] = *(const bf16x8*)(pb + j * 16 * 32);                              \
    _Pragma("unroll") for (int i = 0; i < 4; ++i)                                 \
        _Pragma("unroll") for (int j = 0; j < 4; ++j)                             \
            acc[i][j] = mfma_bf16(af[i], bfv[j], acc[i][j]);                      \
  }

// QKV GEMM: N=3072. Epilogue scatters to Q (scaled by 1/8) [BH][T][64], K [BH][T][64], VT [BH][64][T].
__global__ __launch_bounds__(256) void gemm_qkv(
    const unsigned short* __restrict__ A, const unsigned short* __restrict__ Bt,
    const float* __restrict__ bias,
    unsigned short* __restrict__ Qo, unsigned short* __restrict__ Ko,
    unsigned short* __restrict__ VTo) {
  GEMM_CORE(A, Bt)
#pragma unroll
  for (int i = 0; i < 4; ++i) {
    int mb = m0 + wr * 64 + i * 16 + 4 * (l >> 4);
    int bidx = mb >> 10;
    int t = mb & 1023;
#pragma unroll
    for (int j = 0; j < 4; ++j) {
      int n = n0 + wc * 64 + j * 16 + (l & 15);
      float bv = bias[n];
      int part = n >> 10;
      int nn = n & 1023;
      int h = nn >> 6, d = nn & 63;
      if (part == 2) {
        alignas(8) unsigned short pk[4];
#pragma unroll
        for (int r = 0; r < 4; ++r) pk[r] = f2bf(acc[i][j][r] + bv);
        *(ushort4*)&VTo[((size_t)(bidx * NHEAD + h) * HDIM + d) * SEQ + t] =
            *(const ushort4*)pk;
      } else {
        unsigned short* dst = (part == 0) ? Qo : Ko;
        float scl = (part == 0) ? 0.125f : 1.0f;   // fold 1/sqrt(hd) into Q
        size_t base = ((size_t)(bidx * NHEAD + h) * SEQ + t) * HDIM + d;
#pragma unroll
        for (int r = 0; r < 4; ++r) dst[base + (size_t)r * HDIM] = f2bf((acc[i][j][r] + bv) * scl);
      }
    }
  }
}

// Proj GEMM: N=1024, f32 output + bias.
__global__ __launch_bounds__(256) void gemm_proj(
    const unsigned short* __restrict__ A, const unsigned short* __restrict__ Bt,
    const float* __restrict__ bias, float* __restrict__ Out) {
  GEMM_CORE(A, Bt)
#pragma unroll
  for (int i = 0; i < 4; ++i) {
    int mb = m0 + wr * 64 + i * 16 + 4 * (l >> 4);
#pragma unroll
    for (int j = 0; j < 4; ++j) {
      int n = n0 + wc * 64 + j * 16 + (l & 15);
      float bv = bias[n];
#pragma unroll
      for (int r = 0; r < 4; ++r)
        Out[(size_t)(mb + r) * N_EMBD + n] = acc[i][j][r] + bv;
    }
  }
}

// ---------------- flash-style causal attention ----------------
// Swapped QK^T (S^T = K·Q^T): lane holds 16 kv of one q-row -> in-lane row reduce.
// Defer-max (THR=8): rescale almost never fires; running sum is per-lane partial, 0 shfl/iter.
// K/V LDS-staged, double-buffered, counted vmcnt, XOR-swizzled via pre-swizzled global source.
__global__ __launch_bounds__(256) void attn_kernel(
    const unsigned short* __restrict__ Q, const unsigned short* __restrict__ Kv,
    const unsigned short* __restrict__ VT, unsigned short* __restrict__ Y) {
  __shared__ unsigned short Kt[2][4096];
  __shared__ unsigned short Vt[2][4096];
  __shared__ unsigned short p_lds[4 * 32 * 72];
  __shared__ float smx[4][32];
  int tid = threadIdx.x, l = tid & 63, w = tid >> 6;
  // block swizzle: XCD k owns heads 16k..16k+15; within a head, long q-blocks (qi=7) first
  int orig = blockIdx.x;
  int swz = (orig & 7) * 128 + (orig >> 3);
  int bh = swz >> 3;
  int qi = 7 - (swz & 7);
  int b = bh >> 4, h = bh & 15;
  int q0 = qi * 128;
  int wq = q0 + w * 32;
  const unsigned short* Qb = Q + (size_t)bh * SEQ * HDIM;
  const char* Kc = (const char*)(Kv + (size_t)bh * SEQ * HDIM);
  const char* Vc = (const char*)(VT + (size_t)bh * HDIM * SEQ);
  unsigned short* pw = &p_lds[w * 32 * 72];
  const int g = l >> 4;     // 16-lane group
  const int fr = l & 15;

  // staging geometry: LDS linear, global source pre-swizzled so
  // LDS[row*128 + (c ^ ((row&7)<<4))] = G[row][c].
  const int P0 = tid * 16, P1 = tid * 16 + 4096;
  const int r0 = P0 >> 7, r1 = P1 >> 7;
  const int s0 = (P0 & 127) ^ ((r0 & 7) << 4);
  const int s1 = (P1 & 127) ^ ((r1 & 7) << 4);
  const char* Kg0 = Kc + r0 * 128 + s0;
  const char* Kg1 = Kc + r1 * 128 + s1;
  const char* Vg0 = Vc + (size_t)r0 * 2048 + s0;
  const char* Vg1 = Vc + (size_t)r1 * 2048 + s1;

  // per-lane swizzled fragment-read col base; ^ (ik<<6) selects k-half
  const int bc = (16 * g) ^ ((l & 7) << 4);

  bf16x8 aq[2][2];
#pragma unroll
  for (int i = 0; i < 2; ++i)
#pragma unroll
    for (int ik = 0; ik < 2; ++ik)
      aq[i][ik] = *(const bf16x8*)&Qb[(size_t)(wq + i * 16 + fr) * HDIM + ik * 32 + 8 * g];

  float mrun[2], lpart[2];
  mrun[0] = mrun[1] = -3.0e38f;
  lpart[0] = lpart[1] = 0.0f;
  f32x4 acc_o[2][4];
#pragma unroll
  for (int i = 0; i < 2; ++i)
#pragma unroll
    for (int jd = 0; jd < 4; ++jd)
#pragma unroll
      for (int r = 0; r < 4; ++r) acc_o[i][jd][r] = 0.0f;

  const int n_it = (q0 + 128) >> 6;  // block-uniform

  // prologue: stage tile 0
  gload_lds16((const unsigned short*)(Kg0), &Kt[0][P0 >> 1]);
  gload_lds16((const unsigned short*)(Kg1), &Kt[0][P1 >> 1]);
  gload_lds16((const unsigned short*)(Vg0), &Vt[0][P0 >> 1]);
  gload_lds16((const unsigned short*)(Vg1), &Vt[0][P1 >> 1]);

  for (int it = 0; it < n_it; ++it) {
    const int kv0 = it << 6;
    const int cur = it & 1;
    if (it + 1 < n_it) {
      const int nx = kv0 + 64;
      gload_lds16((const unsigned short*)(Kg0 + nx * 128), &Kt[cur ^ 1][P0 >> 1]);
      gload_lds16((const unsigned short*)(Kg1 + nx * 128), &Kt[cur ^ 1][P1 >> 1]);
      gload_lds16((const unsigned short*)(Vg0 + nx * 2),   &Vt[cur ^ 1][P0 >> 1]);
      gload_lds16((const unsigned short*)(Vg1 + nx * 2),   &Vt[cur ^ 1][P1 >> 1]);
      asm volatile("s_waitcnt vmcnt(4)" ::: "memory");
    } else {
      asm volatile("s_waitcnt vmcnt(0)" ::: "memory");
    }
    __builtin_amdgcn_sched_barrier(0);
    __builtin_amdgcn_s_barrier();
    __builtin_amdgcn_sched_barrier(0);

    const char* Kbuf = (const char*)Kt[cur];
    const char* Vbuf = (const char*)Vt[cur];

    // S^T[kv][q]: s2[it2][j], lane holds kv = kv0 + j*16 + 4g + r, q = wq + it2*16 + fr
    f32x4 s2[2][4];
#pragma unroll
    for (int i = 0; i < 2; ++i)
#pragma unroll
      for (int j = 0; j < 4; ++j)
#pragma unroll
        for (int r = 0; r < 4; ++r) s2[i][j][r] = 0.0f;

    __builtin_amdgcn_s_setprio(1);
#pragma unroll
    for (int ik = 0; ik < 2; ++ik) {
#pragma unroll
      for (int j = 0; j < 4; ++j) {
        bf16x8 bk = *(const bf16x8*)(Kbuf + (j * 16 + fr) * 128 + (bc ^ (ik << 6)));
#pragma unroll
        for (int i = 0; i < 2; ++i) s2[i][j] = mfma_bf16(bk, aq[i][ik], s2[i][j]);
      }
    }
    __builtin_amdgcn_s_setprio(0);

    bool need_mask = (kv0 + 63) > wq;
    if (need_mask) {
#pragma unroll
      for (int i = 0; i < 2; ++i) {
        int q = wq + i * 16 + fr;
#pragma unroll
        for (int j = 0; j < 4; ++j)
#pragma unroll
          for (int r = 0; r < 4; ++r) {
            int kv = kv0 + j * 16 + 4 * g + r;
            if (kv > q) s2[i][j][r] = -3.0e38f;
          }
      }
    }

    // per-row max: in-lane tree + 2 shfl (cross-g)
    float pm[2];
#pragma unroll
    for (int i = 0; i < 2; ++i) {
      float m01 = fmaxf(fmaxf(s2[i][0][0], s2[i][0][1]), fmaxf(s2[i][0][2], s2[i][0][3]));
      float m11 = fmaxf(fmaxf(s2[i][1][0], s2[i][1][1]), fmaxf(s2[i][1][2], s2[i][1][3]));
      float m21 = fmaxf(fmaxf(s2[i][2][0], s2[i][2][1]), fmaxf(s2[i][2][2], s2[i][2][3]));
      float m31 = fmaxf(fmaxf(s2[i][3][0], s2[i][3][1]), fmaxf(s2[i][3][2], s2[i][3][3]));
      float mm = fmaxf(fmaxf(m01, m11), fmaxf(m21, m31));
      mm = fmaxf(mm, __shfl_xor(mm, 16, 64));
      mm = fmaxf(mm, __shfl_xor(mm, 32, 64));
      pm[i] = mm;
    }

    bool okl = (pm[0] <= mrun[0] + 8.0f) && (pm[1] <= mrun[1] + 8.0f);
    if (!__all(okl)) {   // rare rescale path (fires ~only on first tile)
#pragma unroll
      for (int i = 0; i < 2; ++i) {
        float mn = fmaxf(mrun[i], pm[i]);
        float sc = __expf(mrun[i] - mn);
        mrun[i] = mn;
        lpart[i] *= sc;
        if (g == 0) smx[w][i * 16 + fr] = sc;
      }
      asm volatile("s_waitcnt lgkmcnt(0)" ::: "memory");
#pragma unroll
      for (int i = 0; i < 2; ++i)
#pragma unroll
        for (int r = 0; r < 4; ++r) {
          float sc = smx[w][i * 16 + 4 * g + r];
#pragma unroll
          for (int jd = 0; jd < 4; ++jd) acc_o[i][jd][r] *= sc;
        }
    }

    // P = exp(S - m); per-lane partial sum; vectorized b64 P-writes
#pragma unroll
    for (int i = 0; i < 2; ++i) {
#pragma unroll
      for (int j = 0; j < 4; ++j) {
        float p0 = __expf(s2[i][j][0] - mrun[i]);
        float p1 = __expf(s2[i][j][1] - mrun[i]);
        float p2 = __expf(s2[i][j][2] - mrun[i]);
        float p3 = __expf(s2[i][j][3] - mrun[i]);
        lpart[i] += (p0 + p1) + (p2 + p3);
        ushort4 pk;
        pk.x = f2bf(p0); pk.y = f2bf(p1); pk.z = f2bf(p2); pk.w = f2bf(p3);
        *(ushort4*)&pw[(i * 16 + fr) * 72 + j * 16 + 4 * g] = pk;
      }
    }

    __builtin_amdgcn_s_setprio(1);
#pragma unroll
    for (int ik2 = 0; ik2 < 2; ++ik2) {
      bf16x8 ap[2];
#pragma unroll
      for (int i = 0; i < 2; ++i)
        ap[i] = *(const bf16x8*)&pw[(i * 16 + fr) * 72 + ik2 * 32 + 8 * g];
#pragma unroll
      for (int jd = 0; jd < 4; ++jd) {
        bf16x8 bv = *(const bf16x8*)(Vbuf + (jd * 16 + fr) * 128 + (bc ^ (ik2 << 6)));
#pragma unroll
        for (int i = 0; i < 2; ++i) acc_o[i][jd] = mfma_bf16(ap[i], bv, acc_o[i][jd]);
      }
    }
    __builtin_amdgcn_s_setprio(0);

    asm volatile("s_waitcnt lgkmcnt(0)" ::: "memory");
    __builtin_amdgcn_sched_barrier(0);
    __builtin_amdgcn_s_barrier();
    __builtin_amdgcn_sched_barrier(0);
  }

  // finalize row sums: 2 shfl + LDS broadcast to O-layout
#pragma unroll
  for (int i = 0; i < 2; ++i) {
    float t = lpart[i];
    t += __shfl_xor(t, 16, 64);
    t += __shfl_xor(t, 32, 64);
    if (g == 0) smx[w][i * 16 + fr] = t;
  }
  asm volatile("s_waitcnt lgkmcnt(0)" ::: "memory");
#pragma unroll
  for (int i = 0; i < 2; ++i)
#pragma unroll
    for (int r = 0; r < 4; ++r) {
      float inv = 1.0f / smx[w][i * 16 + 4 * g + r];
      int q = wq + i * 16 + 4 * g + r;
#pragma unroll
      for (int jd = 0; jd < 4; ++jd)
        Y[((size_t)b * SEQ + q) * N_EMBD + h * HDIM + jd * 16 + fr] =
            f2bf(acc_o[i][jd][r] * inv);
    }
}

// ---------------- launcher ----------------
extern "C" void kernel_launch(void* const* d_in, const int* in_sizes, int n_in,
                              void* d_out, int out_size, void* d_ws, size_t ws_size,
                              hipStream_t stream) {
  (void)in_sizes; (void)n_in; (void)out_size; (void)ws_size;
  const float* x      = (const float*)d_in[0];
  const float* w_attn = (const float*)d_in[1];
  const float* b_attn = (const float*)d_in[2];
  const float* w_proj = (const float*)d_in[3];
  const float* b_proj = (const float*)d_in[4];
  float* out = (float*)d_out;

  char* ws = (char*)d_ws;
  size_t off = 0;
  auto carve = [&](size_t bytes) -> char* {
    char* p = ws + off;
    off += (bytes + 255) & ~(size_t)255;
    return p;
  };
  unsigned short* xb     = (unsigned short*)carve((size_t)MROWS * N_EMBD * 2);
  unsigned short* wTattn = (unsigned short*)carve((size_t)3 * N_EMBD * N_EMBD * 2);
  unsigned short* wTproj = (unsigned short*)carve((size_t)N_EMBD * N_EMBD * 2);
  unsigned short* Qb     = (unsigned short*)carve((size_t)MROWS * N_EMBD * 2);
  unsigned short* Kb     = (unsigned short*)carve((size_t)MROWS * N_EMBD * 2);
  unsigned short* VTb    = (unsigned short*)carve((size_t)MROWS * N_EMBD * 2);
  unsigned short* Yb     = (unsigned short*)carve((size_t)MROWS * N_EMBD * 2);

  cast_f32_bf16<<<dim3(MROWS * N_EMBD / 1024), 256, 0, stream>>>(x, xb, MROWS * N_EMBD);
  transpose_cast<<<dim3(3 * N_EMBD / 64, N_EMBD / 64), 256, 0, stream>>>(w_attn, wTattn, N_EMBD, 3 * N_EMBD);
  transpose_cast<<<dim3(N_EMBD / 64, N_EMBD / 64), 256, 0, stream>>>(w_proj, wTproj, N_EMBD, N_EMBD);
  gemm_qkv<<<dim3(3 * N_EMBD / 128, MROWS / 128), 256, 0, stream>>>(xb, wTattn, b_attn, Qb, Kb, VTb);
  attn_kernel<<<dim3(BATCH * NHEAD * (SEQ / 128)), 256, 0, stream>>>(Qb, Kb, VTb, Yb);
  gemm_proj<<<dim3(N_EMBD / 128, MROWS / 128), 256, 0, stream>>>(Yb, wTproj, b_proj, out);
}

// Round 5
// 189.635 us; speedup vs baseline: 1.9910x; 1.0430x over previous
//
#include <hip/hip_runtime.h>
#include <stdint.h>

#define N_EMBD 1024
#define NHEAD  16
#define HDIM   64
#define BATCH  8
#define SEQ    1024
#define MROWS  (BATCH*SEQ)   // 8192

typedef __bf16 bf16x8 __attribute__((ext_vector_type(8)));
typedef float  f32x4  __attribute__((ext_vector_type(4)));

__device__ inline unsigned short f2bf(float f) {
  uint32_t u = __float_as_uint(f);
  u += 0x7FFFu + ((u >> 16) & 1u);   // RNE; inputs are finite
  return (unsigned short)(u >> 16);
}

__device__ inline f32x4 mfma_bf16(bf16x8 a, bf16x8 b, f32x4 c) {
  return __builtin_amdgcn_mfma_f32_16x16x32_bf16(a, b, c, 0, 0, 0);
}

__device__ inline void gload_lds16(const unsigned short* g, unsigned short* l) {
  __builtin_amdgcn_global_load_lds(
      (const __attribute__((address_space(1))) void*)g,
      (__attribute__((address_space(3))) void*)l,
      16, 0, 0);
}

// ---------------- cast f32 -> bf16 (vectorized) ----------------
__global__ __launch_bounds__(256) void cast_f32_bf16(
    const float* __restrict__ in, unsigned short* __restrict__ out, int n) {
  int i = (blockIdx.x * 256 + threadIdx.x) * 4;
  if (i >= n) return;
  float4 v = *(const float4*)(in + i);
  ushort4 o;
  o.x = f2bf(v.x); o.y = f2bf(v.y); o.z = f2bf(v.z); o.w = f2bf(v.w);
  *(ushort4*)(out + i) = o;
}

// ---------------- transpose + cast: in [K][N] f32 -> out [N][K] bf16 ----------------
__global__ __launch_bounds__(256) void transpose_cast(
    const float* __restrict__ in, unsigned short* __restrict__ out, int K, int N) {
  __shared__ unsigned short tile[64 * 72];
  int k0 = blockIdx.y * 64, n0 = blockIdx.x * 64;
  int t = threadIdx.x;
  {
    int col = (t & 15) * 4;
#pragma unroll
    for (int it = 0; it < 4; ++it) {
      int row = (t >> 4) + it * 16;
      float4 v = *(const float4*)(in + (size_t)(k0 + row) * N + n0 + col);
      ushort4 o;
      o.x = f2bf(v.x); o.y = f2bf(v.y); o.z = f2bf(v.z); o.w = f2bf(v.w);
      *(ushort4*)&tile[row * 72 + col] = o;
    }
  }
  __syncthreads();
  {
    int kcol = (t & 7) * 8;
#pragma unroll
    for (int it = 0; it < 2; ++it) {
      int nrow = (t >> 3) + it * 32;
      alignas(16) unsigned short tmp[8];
#pragma unroll
      for (int j = 0; j < 8; ++j) tmp[j] = tile[(kcol + j) * 72 + nrow];
      *(uint4*)(out + (size_t)(n0 + nrow) * K + k0 + kcol) = *(const uint4*)tmp;
    }
  }
}

// ---------------- GEMM v2: 256x128 tile, BK=64, 8 waves (4Mx2N), dbuf LDS + counted vmcnt,
// T2 XOR-swizzle (LDS linear, pre-swizzled global source), T1 XCD block swizzle, T5 setprio.
// A[M][1024] bf16 row-major, Bt[N][1024] bf16 row-major (N-major). 512 threads.
#define GEMM2_CORE(A_, Bt_, NBX_)                                                 \
  __shared__ unsigned short Al[2][256 * 64];                                      \
  __shared__ unsigned short Bl[2][128 * 64];                                      \
  const int tid = threadIdx.x;                                                    \
  const int l = tid & 63, w = tid >> 6;                                           \
  const int wr = w >> 1, wc = w & 1;                                              \
  const int g = l >> 4, fr = l & 15;                                              \
  const int nwg = NBX_ * 32;                                                      \
  int bid = blockIdx.x;                                                           \
  int swzb = (bid & 7) * (nwg >> 3) + (bid >> 3);   /* bijective: nwg%8==0 */     \
  const int n0 = (swzb % NBX_) * 128;                                             \
  const int m0 = (swzb / NBX_) * 256;                                             \
  f32x4 acc[4][4];                                                                \
  _Pragma("unroll") for (int i = 0; i < 4; ++i)                                   \
      _Pragma("unroll") for (int j = 0; j < 4; ++j)                               \
          _Pragma("unroll") for (int r = 0; r < 4; ++r) acc[i][j][r] = 0.0f;      \
  /* staging: thread owns 16B at LDS byte P=tid*16+it*8192; row=P>>7, col=P&127. */\
  /* source col pre-XORed so LDS[row][c ^ ((row&7)<<4)] = G[row][c]. */           \
  const int a_r = tid >> 3;                                                       \
  const int a_c = ((tid & 7) * 16) ^ ((a_r & 7) << 4);                            \
  const char* Agp = (const char*)A_ + (size_t)(m0 + a_r) * 2048 + a_c;            \
  const char* Bgp = (const char*)Bt_ + (size_t)(n0 + a_r) * 2048 + a_c;           \
  /* fragment read byte offsets (swizzled) */                                     \
  int offA[4][2], offB[4][2];                                                     \
  _Pragma("unroll") for (int m = 0; m < 4; ++m)                                   \
      _Pragma("unroll") for (int ks = 0; ks < 2; ++ks) {                          \
        offA[m][ks] = (wr * 64 + m * 16 + fr) * 128 +                             \
                      ((ks * 64 + g * 16) ^ ((fr & 7) << 4));                     \
        offB[m][ks] = (wc * 64 + m * 16 + fr) * 128 +                             \
                      ((ks * 64 + g * 16) ^ ((fr & 7) << 4));                     \
      }                                                                           \
  /* prologue: stage K-tile 0 into buf 0 */                                       \
  _Pragma("unroll") for (int it = 0; it < 4; ++it)                                \
    gload_lds16((const unsigned short*)(Agp + it * 131072),                       \
                &Al[0][tid * 8 + it * 4096]);                                     \
  _Pragma("unroll") for (int it = 0; it < 2; ++it)                                \
    gload_lds16((const unsigned short*)(Bgp + it * 131072),                       \
                &Bl[0][tid * 8 + it * 4096]);                                     \
  for (int t = 0; t < 16; ++t) {                                                  \
    const int cur = t & 1;                                                        \
    if (t < 15) {                                                                 \
      const int ko = (t + 1) * 128;                                               \
      _Pragma("unroll") for (int it = 0; it < 4; ++it)                            \
        gload_lds16((const unsigned short*)(Agp + it * 131072 + ko),              \
                    &Al[cur ^ 1][tid * 8 + it * 4096]);                           \
      _Pragma("unroll") for (int it = 0; it < 2; ++it)                            \
        gload_lds16((const unsigned short*)(Bgp + it * 131072 + ko),              \
                    &Bl[cur ^ 1][tid * 8 + it * 4096]);                           \
      asm volatile("s_waitcnt vmcnt(6)" ::: "memory");  /* tile t landed */       \
    } else {                                                                      \
      asm volatile("s_waitcnt vmcnt(0)" ::: "memory");                            \
    }                                                                             \
    __builtin_amdgcn_sched_barrier(0);                                            \
    __builtin_amdgcn_s_barrier();                                                 \
    __builtin_amdgcn_sched_barrier(0);                                            \
    const char* Ab = (const char*)&Al[cur][0];                                    \
    const char* Bb = (const char*)&Bl[cur][0];                                    \
    bf16x8 av[4][2], bv[4][2];                                                    \
    _Pragma("unroll") for (int m = 0; m < 4; ++m)                                 \
        _Pragma("unroll") for (int ks = 0; ks < 2; ++ks)                          \
            av[m][ks] = *(const bf16x8*)(Ab + offA[m][ks]);                       \
    _Pragma("unroll") for (int n = 0; n < 4; ++n)                                 \
        _Pragma("unroll") for (int ks = 0; ks < 2; ++ks)                          \
            bv[n][ks] = *(const bf16x8*)(Bb + offB[n][ks]);                       \
    __builtin_amdgcn_s_setprio(1);                                                \
    _Pragma("unroll") for (int m = 0; m < 4; ++m)                                 \
        _Pragma("unroll") for (int n = 0; n < 4; ++n)                             \
            _Pragma("unroll") for (int ks = 0; ks < 2; ++ks)                      \
                acc[m][n] = mfma_bf16(av[m][ks], bv[n][ks], acc[m][n]);           \
    __builtin_amdgcn_s_setprio(0);                                                \
    asm volatile("s_waitcnt lgkmcnt(0)" ::: "memory");                            \
    __builtin_amdgcn_sched_barrier(0);                                            \
    __builtin_amdgcn_s_barrier();  /* buf cur free for t+2's loads */             \
    __builtin_amdgcn_sched_barrier(0);                                            \
  }

// QKV GEMM: N=3072. Epilogue scatters to Q (scaled 1/8) [BH][T][64], K [BH][T][64], VT [BH][64][T].
__global__ __launch_bounds__(512) void gemm_qkv(
    const unsigned short* __restrict__ A, const unsigned short* __restrict__ Bt,
    const float* __restrict__ bias,
    unsigned short* __restrict__ Qo, unsigned short* __restrict__ Ko,
    unsigned short* __restrict__ VTo) {
  GEMM2_CORE(A, Bt, 24)
#pragma unroll
  for (int i = 0; i < 4; ++i) {
    int mb = m0 + wr * 64 + i * 16 + 4 * g;
    int bidx = mb >> 10;
    int t = mb & 1023;
#pragma unroll
    for (int j = 0; j < 4; ++j) {
      int n = n0 + wc * 64 + j * 16 + fr;
      float bv2 = bias[n];
      int part = n >> 10;
      int nn = n & 1023;
      int h = nn >> 6, d = nn & 63;
      if (part == 2) {
        alignas(8) unsigned short pk[4];
#pragma unroll
        for (int r = 0; r < 4; ++r) pk[r] = f2bf(acc[i][j][r] + bv2);
        *(ushort4*)&VTo[((size_t)(bidx * NHEAD + h) * HDIM + d) * SEQ + t] =
            *(const ushort4*)pk;
      } else {
        unsigned short* dst = (part == 0) ? Qo : Ko;
        float scl = (part == 0) ? 0.125f : 1.0f;   // fold 1/sqrt(hd) into Q
        size_t base = ((size_t)(bidx * NHEAD + h) * SEQ + t) * HDIM + d;
#pragma unroll
        for (int r = 0; r < 4; ++r)
          dst[base + (size_t)r * HDIM] = f2bf((acc[i][j][r] + bv2) * scl);
      }
    }
  }
}

// Proj GEMM: N=1024, f32 output + bias.
__global__ __launch_bounds__(512) void gemm_proj(
    const unsigned short* __restrict__ A, const unsigned short* __restrict__ Bt,
    const float* __restrict__ bias, float* __restrict__ Out) {
  GEMM2_CORE(A, Bt, 8)
#pragma unroll
  for (int i = 0; i < 4; ++i) {
    int mb = m0 + wr * 64 + i * 16 + 4 * g;
#pragma unroll
    for (int j = 0; j < 4; ++j) {
      int n = n0 + wc * 64 + j * 16 + fr;
      float bv2 = bias[n];
#pragma unroll
      for (int r = 0; r < 4; ++r)
        Out[(size_t)(mb + r) * N_EMBD + n] = acc[i][j][r] + bv2;
    }
  }
}

// ---------------- flash-style causal attention (unchanged from R3) ----------------
__global__ __launch_bounds__(256) void attn_kernel(
    const unsigned short* __restrict__ Q, const unsigned short* __restrict__ Kv,
    const unsigned short* __restrict__ VT, unsigned short* __restrict__ Y) {
  __shared__ unsigned short Kt[2][4096];
  __shared__ unsigned short Vt[2][4096];
  __shared__ unsigned short p_lds[4 * 32 * 72];
  __shared__ float smx[4][32];
  int tid = threadIdx.x, l = tid & 63, w = tid >> 6;
  int orig = blockIdx.x;
  int swz = (orig & 7) * 128 + (orig >> 3);
  int bh = swz >> 3;
  int qi = 7 - (swz & 7);
  int b = bh >> 4, h = bh & 15;
  int q0 = qi * 128;
  int wq = q0 + w * 32;
  const unsigned short* Qb = Q + (size_t)bh * SEQ * HDIM;
  const char* Kc = (const char*)(Kv + (size_t)bh * SEQ * HDIM);
  const char* Vc = (const char*)(VT + (size_t)bh * HDIM * SEQ);
  unsigned short* pw = &p_lds[w * 32 * 72];
  const int g = l >> 4;
  const int fr = l & 15;

  const int P0 = tid * 16, P1 = tid * 16 + 4096;
  const int r0 = P0 >> 7, r1 = P1 >> 7;
  const int s0 = (P0 & 127) ^ ((r0 & 7) << 4);
  const int s1 = (P1 & 127) ^ ((r1 & 7) << 4);
  const char* Kg0 = Kc + r0 * 128 + s0;
  const char* Kg1 = Kc + r1 * 128 + s1;
  const char* Vg0 = Vc + (size_t)r0 * 2048 + s0;
  const char* Vg1 = Vc + (size_t)r1 * 2048 + s1;

  const int bc = (16 * g) ^ ((l & 7) << 4);

  bf16x8 aq[2][2];
#pragma unroll
  for (int i = 0; i < 2; ++i)
#pragma unroll
    for (int ik = 0; ik < 2; ++ik)
      aq[i][ik] = *(const bf16x8*)&Qb[(size_t)(wq + i * 16 + fr) * HDIM + ik * 32 + 8 * g];

  float mrun[2], lpart[2];
  mrun[0] = mrun[1] = -3.0e38f;
  lpart[0] = lpart[1] = 0.0f;
  f32x4 acc_o[2][4];
#pragma unroll
  for (int i = 0; i < 2; ++i)
#pragma unroll
    for (int jd = 0; jd < 4; ++jd)
#pragma unroll
      for (int r = 0; r < 4; ++r) acc_o[i][jd][r] = 0.0f;

  const int n_it = (q0 + 128) >> 6;

  gload_lds16((const unsigned short*)(Kg0), &Kt[0][P0 >> 1]);
  gload_lds16((const unsigned short*)(Kg1), &Kt[0][P1 >> 1]);
  gload_lds16((const unsigned short*)(Vg0), &Vt[0][P0 >> 1]);
  gload_lds16((const unsigned short*)(Vg1), &Vt[0][P1 >> 1]);

  for (int it = 0; it < n_it; ++it) {
    const int kv0 = it << 6;
    const int cur = it & 1;
    if (it + 1 < n_it) {
      const int nx = kv0 + 64;
      gload_lds16((const unsigned short*)(Kg0 + nx * 128), &Kt[cur ^ 1][P0 >> 1]);
      gload_lds16((const unsigned short*)(Kg1 + nx * 128), &Kt[cur ^ 1][P1 >> 1]);
      gload_lds16((const unsigned short*)(Vg0 + nx * 2),   &Vt[cur ^ 1][P0 >> 1]);
      gload_lds16((const unsigned short*)(Vg1 + nx * 2),   &Vt[cur ^ 1][P1 >> 1]);
      asm volatile("s_waitcnt vmcnt(4)" ::: "memory");
    } else {
      asm volatile("s_waitcnt vmcnt(0)" ::: "memory");
    }
    __builtin_amdgcn_sched_barrier(0);
    __builtin_amdgcn_s_barrier();
    __builtin_amdgcn_sched_barrier(0);

    const char* Kbuf = (const char*)Kt[cur];
    const char* Vbuf = (const char*)Vt[cur];

    f32x4 s2[2][4];
#pragma unroll
    for (int i = 0; i < 2; ++i)
#pragma unroll
      for (int j = 0; j < 4; ++j)
#pragma unroll
        for (int r = 0; r < 4; ++r) s2[i][j][r] = 0.0f;

    __builtin_amdgcn_s_setprio(1);
#pragma unroll
    for (int ik = 0; ik < 2; ++ik) {
#pragma unroll
      for (int j = 0; j < 4; ++j) {
        bf16x8 bk = *(const bf16x8*)(Kbuf + (j * 16 + fr) * 128 + (bc ^ (ik << 6)));
#pragma unroll
        for (int i = 0; i < 2; ++i) s2[i][j] = mfma_bf16(bk, aq[i][ik], s2[i][j]);
      }
    }
    __builtin_amdgcn_s_setprio(0);

    bool need_mask = (kv0 + 63) > wq;
    if (need_mask) {
#pragma unroll
      for (int i = 0; i < 2; ++i) {
        int q = wq + i * 16 + fr;
#pragma unroll
        for (int j = 0; j < 4; ++j)
#pragma unroll
          for (int r = 0; r < 4; ++r) {
            int kv = kv0 + j * 16 + 4 * g + r;
            if (kv > q) s2[i][j][r] = -3.0e38f;
          }
      }
    }

    float pm[2];
#pragma unroll
    for (int i = 0; i < 2; ++i) {
      float m01 = fmaxf(fmaxf(s2[i][0][0], s2[i][0][1]), fmaxf(s2[i][0][2], s2[i][0][3]));
      float m11 = fmaxf(fmaxf(s2[i][1][0], s2[i][1][1]), fmaxf(s2[i][1][2], s2[i][1][3]));
      float m21 = fmaxf(fmaxf(s2[i][2][0], s2[i][2][1]), fmaxf(s2[i][2][2], s2[i][2][3]));
      float m31 = fmaxf(fmaxf(s2[i][3][0], s2[i][3][1]), fmaxf(s2[i][3][2], s2[i][3][3]));
      float mm = fmaxf(fmaxf(m01, m11), fmaxf(m21, m31));
      mm = fmaxf(mm, __shfl_xor(mm, 16, 64));
      mm = fmaxf(mm, __shfl_xor(mm, 32, 64));
      pm[i] = mm;
    }

    bool okl = (pm[0] <= mrun[0] + 8.0f) && (pm[1] <= mrun[1] + 8.0f);
    if (!__all(okl)) {
#pragma unroll
      for (int i = 0; i < 2; ++i) {
        float mn = fmaxf(mrun[i], pm[i]);
        float sc = __expf(mrun[i] - mn);
        mrun[i] = mn;
        lpart[i] *= sc;
        if (g == 0) smx[w][i * 16 + fr] = sc;
      }
      asm volatile("s_waitcnt lgkmcnt(0)" ::: "memory");
#pragma unroll
      for (int i = 0; i < 2; ++i)
#pragma unroll
        for (int r = 0; r < 4; ++r) {
          float sc = smx[w][i * 16 + 4 * g + r];
#pragma unroll
          for (int jd = 0; jd < 4; ++jd) acc_o[i][jd][r] *= sc;
        }
    }

#pragma unroll
    for (int i = 0; i < 2; ++i) {
#pragma unroll
      for (int j = 0; j < 4; ++j) {
        float p0 = __expf(s2[i][j][0] - mrun[i]);
        float p1 = __expf(s2[i][j][1] - mrun[i]);
        float p2 = __expf(s2[i][j][2] - mrun[i]);
        float p3 = __expf(s2[i][j][3] - mrun[i]);
        lpart[i] += (p0 + p1) + (p2 + p3);
        ushort4 pk;
        pk.x = f2bf(p0); pk.y = f2bf(p1); pk.z = f2bf(p2); pk.w = f2bf(p3);
        *(ushort4*)&pw[(i * 16 + fr) * 72 + j * 16 + 4 * g] = pk;
      }
    }

    __builtin_amdgcn_s_setprio(1);
#pragma unroll
    for (int ik2 = 0; ik2 < 2; ++ik2) {
      bf16x8 ap[2];
#pragma unroll
      for (int i = 0; i < 2; ++i)
        ap[i] = *(const bf16x8*)&pw[(i * 16 + fr) * 72 + ik2 * 32 + 8 * g];
#pragma unroll
      for (int jd = 0; jd < 4; ++jd) {
        bf16x8 bv = *(const bf16x8*)(Vbuf + (jd * 16 + fr) * 128 + (bc ^ (ik2 << 6)));
#pragma unroll
        for (int i = 0; i < 2; ++i) acc_o[i][jd] = mfma_bf16(ap[i], bv, acc_o[i][jd]);
      }
    }
    __builtin_amdgcn_s_setprio(0);

    asm volatile("s_waitcnt lgkmcnt(0)" ::: "memory");
    __builtin_amdgcn_sched_barrier(0);
    __builtin_amdgcn_s_barrier();
    __builtin_amdgcn_sched_barrier(0);
  }

#pragma unroll
  for (int i = 0; i < 2; ++i) {
    float t = lpart[i];
    t += __shfl_xor(t, 16, 64);
    t += __shfl_xor(t, 32, 64);
    if (g == 0) smx[w][i * 16 + fr] = t;
  }
  asm volatile("s_waitcnt lgkmcnt(0)" ::: "memory");
#pragma unroll
  for (int i = 0; i < 2; ++i)
#pragma unroll
    for (int r = 0; r < 4; ++r) {
      float inv = 1.0f / smx[w][i * 16 + 4 * g + r];
      int q = wq + i * 16 + 4 * g + r;
#pragma unroll
      for (int jd = 0; jd < 4; ++jd)
        Y[((size_t)b * SEQ + q) * N_EMBD + h * HDIM + jd * 16 + fr] =
            f2bf(acc_o[i][jd][r] * inv);
    }
}

// ---------------- launcher ----------------
extern "C" void kernel_launch(void* const* d_in, const int* in_sizes, int n_in,
                              void* d_out, int out_size, void* d_ws, size_t ws_size,
                              hipStream_t stream) {
  (void)in_sizes; (void)n_in; (void)out_size; (void)ws_size;
  const float* x      = (const float*)d_in[0];
  const float* w_attn = (const float*)d_in[1];
  const float* b_attn = (const float*)d_in[2];
  const float* w_proj = (const float*)d_in[3];
  const float* b_proj = (const float*)d_in[4];
  float* out = (float*)d_out;

  char* ws = (char*)d_ws;
  size_t off = 0;
  auto carve = [&](size_t bytes) -> char* {
    char* p = ws + off;
    off += (bytes + 255) & ~(size_t)255;
    return p;
  };
  unsigned short* xb     = (unsigned short*)carve((size_t)MROWS * N_EMBD * 2);
  unsigned short* wTattn = (unsigned short*)carve((size_t)3 * N_EMBD * N_EMBD * 2);
  unsigned short* wTproj = (unsigned short*)carve((size_t)N_EMBD * N_EMBD * 2);
  unsigned short* Qb     = (unsigned short*)carve((size_t)MROWS * N_EMBD * 2);
  unsigned short* Kb     = (unsigned short*)carve((size_t)MROWS * N_EMBD * 2);
  unsigned short* VTb    = (unsigned short*)carve((size_t)MROWS * N_EMBD * 2);
  unsigned short* Yb     = (unsigned short*)carve((size_t)MROWS * N_EMBD * 2);

  cast_f32_bf16<<<dim3(MROWS * N_EMBD / 1024), 256, 0, stream>>>(x, xb, MROWS * N_EMBD);
  transpose_cast<<<dim3(3 * N_EMBD / 64, N_EMBD / 64), 256, 0, stream>>>(w_attn, wTattn, N_EMBD, 3 * N_EMBD);
  transpose_cast<<<dim3(N_EMBD / 64, N_EMBD / 64), 256, 0, stream>>>(w_proj, wTproj, N_EMBD, N_EMBD);
  gemm_qkv<<<dim3(24 * 32), 512, 0, stream>>>(xb, wTattn, b_attn, Qb, Kb, VTb);
  attn_kernel<<<dim3(BATCH * NHEAD * (SEQ / 128)), 256, 0, stream>>>(Qb, Kb, VTb, Yb);
  gemm_proj<<<dim3(8 * 32), 512, 0, stream>>>(Yb, wTproj, b_proj, out);
}